// Round 1
// baseline (871.167 us; speedup 1.0000x reference)
//
#include <hip/hip_runtime.h>
#include <math.h>

// AutoCorrelation (Autoformer) for B=8, H=8, L=4096, D=64, top_k=8.
// Phase A: cross-spectra T[b,h,f] = sum_{d-pairs} FFT(Qpair) * conj(FFT(Kpair))
// Phase B: per-b inverse FFT of sum_h T -> mean_value[b,tau]
// Phase C: top-8 lags of batch-mean + per-b softmax weights
// Phase D: out[b,h,l,:] = sum_k w[b,k] * V[b,h,(l+idx_k)%L,:]

#define LSEQ 4096
#define DDIM 64
#define NB 8
#define NH 8
#define NBH 64
#define TOPK 8

__device__ __forceinline__ float2 cadd(float2 a, float2 b){ return make_float2(a.x+b.x, a.y+b.y); }
__device__ __forceinline__ float2 csub(float2 a, float2 b){ return make_float2(a.x-b.x, a.y-b.y); }
__device__ __forceinline__ float2 cmul(float2 a, float2 b){ return make_float2(a.x*b.x - a.y*b.y, a.x*b.y + a.y*b.x); }
__device__ __forceinline__ float2 cmulc(float2 a, float2 b){ // a * conj(b)
    return make_float2(a.x*b.x + a.y*b.y, a.y*b.x - a.x*b.y); }

// ---------------- Phase A: forward FFTs + cross-spectrum accumulation ----------
// grid 64 (one per (b,h)), block 512 (team 0: Q-FFT, team 1: K-FFT)
__global__ __launch_bounds__(512) void corr_fft_kernel(
    const float* __restrict__ Q, const float* __restrict__ K,
    float2* __restrict__ Tout)
{
    __shared__ float2 bufs[2][LSEQ];   // 2 x 32KB = 64KB
    const int bh   = blockIdx.x;
    const int tid  = threadIdx.x;
    const int team = tid >> 8;         // 0 -> Q, 1 -> K
    const int ttid = tid & 255;
    const float* src  = team ? K : Q;
    const float* base = src + (size_t)bh * (LSEQ * DDIM);
    float2* buf = bufs[team];

    // per-thread cross-spectrum accumulator: f = tid + 512*j
    float2 Tacc[8];
#pragma unroll
    for (int j = 0; j < 8; ++j) Tacc[j] = make_float2(0.f, 0.f);

    for (int p = 0; p < 32; ++p) {
        // load packed complex signal: (chan 2p, chan 2p+1)
        const float* colbase = base + 2 * p;
        for (int t = ttid; t < LSEQ; t += 256) {
            buf[t] = *reinterpret_cast<const float2*>(colbase + (size_t)t * DDIM);
        }
        __syncthreads();

        // radix-4 DIF forward FFT (output in base-4 digit-reversed order)
        for (int ls = 12; ls >= 2; ls -= 2) {
            const int qq = 1 << (ls - 2);
#pragma unroll
            for (int vv = 0; vv < 4; ++vv) {
                const int v   = ttid + (vv << 8);      // 1024 butterflies/stage
                const int blk = v >> (ls - 2);
                const int j   = v & (qq - 1);
                const int bo  = (blk << ls) + j;
                float2 a0 = buf[bo], a1 = buf[bo + qq], a2 = buf[bo + 2*qq], a3 = buf[bo + 3*qq];
                float2 t0 = cadd(a0, a2), t1 = csub(a0, a2);
                float2 t2 = cadd(a1, a3), t3 = csub(a1, a3);
                float2 y0 = cadd(t0, t2);
                float2 y1 = make_float2(t1.x + t3.y, t1.y - t3.x);  // t1 - i*t3
                float2 y2 = csub(t0, t2);
                float2 y3 = make_float2(t1.x - t3.y, t1.y + t3.x);  // t1 + i*t3
                const float ang = -6.2831853071795864769f * (float)j / (float)(1 << ls);
                float sn, cs; sincosf(ang, &sn, &cs);
                float2 w1 = make_float2(cs, sn);
                float2 w2 = cmul(w1, w1);
                float2 w3 = cmul(w2, w1);
                buf[bo]        = y0;
                buf[bo + qq]   = cmul(y1, w1);
                buf[bo + 2*qq] = cmul(y2, w2);
                buf[bo + 3*qq] = cmul(y3, w3);
            }
            __syncthreads();
        }

        // T += X * conj(Y)  (elementwise, permuted order is fine)
#pragma unroll
        for (int j = 0; j < 8; ++j) {
            const int f = tid + (j << 9);
            float2 pr = cmulc(bufs[0][f], bufs[1][f]);
            Tacc[j].x += pr.x; Tacc[j].y += pr.y;
        }
        __syncthreads();   // before next iteration overwrites buf
    }

    float2* To = Tout + (size_t)bh * LSEQ;
#pragma unroll
    for (int j = 0; j < 8; ++j) To[tid + (j << 9)] = Tacc[j];
}

// ---------------- Phase B: sum over h + inverse FFT -> mean_value[b,tau] -------
// grid 8 (one per b), block 256
__global__ __launch_bounds__(256) void icorr_kernel(
    const float2* __restrict__ Tin, float* __restrict__ mv)
{
    __shared__ float2 z[LSEQ];   // 32KB
    const int b   = blockIdx.x;
    const int tid = threadIdx.x;

    for (int f = tid; f < LSEQ; f += 256) {
        float2 acc = make_float2(0.f, 0.f);
#pragma unroll
        for (int h = 0; h < NH; ++h) {
            float2 v = Tin[(size_t)(b * NH + h) * LSEQ + f];
            acc.x += v.x; acc.y += v.y;
        }
        z[f] = acc;
    }
    __syncthreads();

    // exact inverse of the DIF algorithm: stages len = 4 .. 4096,
    // conjugate twiddle applied to inputs, inverse radix-4 butterfly
    for (int ls = 2; ls <= 12; ls += 2) {
        const int qq = 1 << (ls - 2);
#pragma unroll
        for (int vv = 0; vv < 4; ++vv) {
            const int v   = tid + (vv << 8);
            const int blk = v >> (ls - 2);
            const int j   = v & (qq - 1);
            const int bo  = (blk << ls) + j;
            const float ang = 6.2831853071795864769f * (float)j / (float)(1 << ls);
            float sn, cs; sincosf(ang, &sn, &cs);
            float2 w1 = make_float2(cs, sn);
            float2 w2 = cmul(w1, w1);
            float2 w3 = cmul(w2, w1);
            float2 u0 = z[bo];
            float2 u1 = cmul(z[bo + qq],   w1);
            float2 u2 = cmul(z[bo + 2*qq], w2);
            float2 u3 = cmul(z[bo + 3*qq], w3);
            float2 t0 = cadd(u0, u2), t1 = csub(u0, u2);
            float2 t2 = cadd(u1, u3), t3 = csub(u1, u3);
            z[bo]        = cadd(t0, t2);
            z[bo + qq]   = make_float2(t1.x - t3.y, t1.y + t3.x);  // t1 + i*t3
            z[bo + 2*qq] = csub(t0, t2);
            z[bo + 3*qq] = make_float2(t1.x + t3.y, t1.y - t3.x);  // t1 - i*t3
        }
        __syncthreads();
    }

    const float scale = 1.0f / (4096.0f * 512.0f);  // 1/N (ifft) * 1/(H*D) (mean)
    for (int t = tid; t < LSEQ; t += 256) mv[b * LSEQ + t] = z[t].x * scale;
}

// ---------------- Phase C: top-8 + softmax weights -----------------------------
// grid 1, block 256
__global__ __launch_bounds__(256) void topk_kernel(
    const float* __restrict__ mv, int* __restrict__ idx_out, float* __restrict__ w_out)
{
    __shared__ float gsm[LSEQ];   // 16KB
    __shared__ float rv[256];
    __shared__ int   ri[256];
    __shared__ int   topidx[TOPK];
    const int tid = threadIdx.x;

    for (int f = tid; f < LSEQ; f += 256) {
        float s = 0.f;
#pragma unroll
        for (int b = 0; b < NB; ++b) s += mv[b * LSEQ + f];
        gsm[f] = s;   // mean over b is monotone scaling -> argmax unchanged
    }
    __syncthreads();

    for (int k = 0; k < TOPK; ++k) {
        float bv = -INFINITY; int bi = -1;
        for (int f = tid; f < LSEQ; f += 256) {
            float v = gsm[f];
            if (v > bv) { bv = v; bi = f; }
        }
        rv[tid] = bv; ri[tid] = bi;
        __syncthreads();
        for (int s2 = 128; s2 > 0; s2 >>= 1) {
            if (tid < s2) {
                if (rv[tid + s2] > rv[tid]) { rv[tid] = rv[tid + s2]; ri[tid] = ri[tid + s2]; }
            }
            __syncthreads();
        }
        if (tid == 0) { topidx[k] = ri[0]; gsm[ri[0]] = -INFINITY; }
        __syncthreads();
    }

    if (tid < NB) {
        const int b = tid;
        float wv[TOPK]; float mx = -INFINITY;
#pragma unroll
        for (int k = 0; k < TOPK; ++k) { wv[k] = mv[b * LSEQ + topidx[k]]; mx = fmaxf(mx, wv[k]); }
        float se = 0.f;
#pragma unroll
        for (int k = 0; k < TOPK; ++k) { wv[k] = expf(wv[k] - mx); se += wv[k]; }
#pragma unroll
        for (int k = 0; k < TOPK; ++k) w_out[b * TOPK + k] = wv[k] / se;
    }
    if (tid < TOPK) idx_out[tid] = topidx[tid];
}

// ---------------- Phase D: weighted circular-shift gather ----------------------
// grid B*H*(L/16) = 16384, block 256; thread -> (row, float4-slot)
__global__ __launch_bounds__(256) void gather_kernel(
    const float* __restrict__ V, const int* __restrict__ idxs,
    const float* __restrict__ w, float* __restrict__ out)
{
    const int blk = blockIdx.x;
    const int bh  = blk >> 8;            // 0..63
    const int l0  = (blk & 255) << 4;    // row base, 16 rows/block
    const int b   = bh >> 3;

    __shared__ int   sidx[TOPK];
    __shared__ float sw[TOPK];
    if (threadIdx.x < TOPK) {
        sidx[threadIdx.x] = idxs[threadIdx.x];
        sw[threadIdx.x]   = w[b * TOPK + threadIdx.x];
    }
    __syncthreads();

    const float4* Vb = reinterpret_cast<const float4*>(V + (size_t)bh * (LSEQ * DDIM));
    float4*       Ob = reinterpret_cast<float4*>(out + (size_t)bh * (LSEQ * DDIM));
    const int r  = threadIdx.x >> 4;     // 0..15
    const int qd = threadIdx.x & 15;     // 0..15 (16 float4 per 64-float row)
    const int l  = l0 + r;

    float4 acc = make_float4(0.f, 0.f, 0.f, 0.f);
#pragma unroll
    for (int k = 0; k < TOPK; ++k) {
        const int lv = (l + sidx[k]) & (LSEQ - 1);
        const float4 vv = Vb[(size_t)lv * 16 + qd];
        const float wk = sw[k];
        acc.x += wk * vv.x; acc.y += wk * vv.y;
        acc.z += wk * vv.z; acc.w += wk * vv.w;
    }
    Ob[(size_t)l * 16 + qd] = acc;
}

extern "C" void kernel_launch(void* const* d_in, const int* in_sizes, int n_in,
                              void* d_out, int out_size, void* d_ws, size_t ws_size,
                              hipStream_t stream)
{
    const float* Q = (const float*)d_in[0];
    const float* K = (const float*)d_in[1];
    const float* V = (const float*)d_in[2];
    float* out = (float*)d_out;

    char* ws = (char*)d_ws;
    float2* T   = (float2*)ws;                                   // 64*4096*8B = 2MB
    float*  mv  = (float*)(ws + (size_t)NBH * LSEQ * sizeof(float2));   // 8*4096*4B = 128KB
    int*    idx = (int*)((char*)mv + (size_t)NB * LSEQ * sizeof(float));
    float*  w   = (float*)((char*)idx + 64);                     // 8 ints (padded)

    corr_fft_kernel<<<dim3(NBH), dim3(512), 0, stream>>>(Q, K, T);
    icorr_kernel  <<<dim3(NB),  dim3(256), 0, stream>>>(T, mv);
    topk_kernel   <<<dim3(1),   dim3(256), 0, stream>>>(mv, idx, w);
    gather_kernel <<<dim3(NB * NH * (LSEQ / 16)), dim3(256), 0, stream>>>(V, idx, w, out);
}

// Round 2
// 424.362 us; speedup vs baseline: 2.0529x; 2.0529x over previous
//
#include <hip/hip_runtime.h>
#include <math.h>

// AutoCorrelation (Autoformer) for B=8, H=8, L=4096, D=64, top_k=8.
// Phase A: cross-spectra summed over h and d: Tb[b,f] = sum_{h,d-pairs} FFT(Qpair)*conj(FFT(Kpair))
//          (512 blocks; 4 d-pairs per block; float atomicAdd reduction)
// Phase B: per-b inverse FFT -> mean_value[b,tau]
// Phase C: top-8 lags of batch-mean + per-b softmax weights
// Phase D: out[b,h,l,:] = sum_k w[b,k] * V[b,h,(l+idx_k)%L,:]

#define LSEQ 4096
#define DDIM 64
#define NB 8
#define NH 8
#define TOPK 8

// LDS bank swizzle for float2 elements: uniform 4-lane/slot (minimum for b64)
// across all radix-4 strides {1,4,16,64,256,1024} and linear access.
#define SWZ(i) ((i) ^ (((i) >> 4) & 15))

__device__ __forceinline__ float2 cadd(float2 a, float2 b){ return make_float2(a.x+b.x, a.y+b.y); }
__device__ __forceinline__ float2 csub(float2 a, float2 b){ return make_float2(a.x-b.x, a.y-b.y); }
__device__ __forceinline__ float2 cmul(float2 a, float2 b){ return make_float2(a.x*b.x - a.y*b.y, a.x*b.y + a.y*b.x); }

// ---------------- Phase A -----------------------------------------------------
// grid 512: block = (bh, q8); team 0 (threads 0..255): Q-FFT, team 1: K-FFT.
// Each block handles d-pairs {4*q8 .. 4*q8+3} (channels 8*q8 .. 8*q8+7).
__global__ __launch_bounds__(512, 4) void corr_fft_kernel(
    const float* __restrict__ Q, const float* __restrict__ K,
    float2* __restrict__ Tb)
{
    __shared__ float2 bufs[2][LSEQ];   // 2 x 32KB = 64KB
    const int blk  = blockIdx.x;
    const int bh   = blk >> 3;
    const int q8   = blk & 7;
    const int b    = bh >> 3;
    const int tid  = threadIdx.x;
    const int team = tid >> 8;
    const int ttid = tid & 255;
    const float* src  = team ? K : Q;
    const float* base = src + (size_t)bh * (LSEQ * DDIM) + q8 * 8;
    float2* buf = bufs[team];

    float2 Tacc[8];
#pragma unroll
    for (int j = 0; j < 8; ++j) Tacc[j] = make_float2(0.f, 0.f);

    float2 r1[16], r2[16], r3[16];

    auto fftfwd = [&]() {   // radix-4 DIF, natural -> digit-reversed order
        for (int ls = 12; ls >= 2; ls -= 2) {
            const int qq = 1 << (ls - 2);
            const float fac = -6.2831853071795864769f / (float)(1 << ls);
#pragma unroll
            for (int vv = 0; vv < 4; ++vv) {
                const int v  = ttid + (vv << 8);
                const int bk = v >> (ls - 2);
                const int j  = v & (qq - 1);
                const int bo = (bk << ls) + j;
                float2 a0 = buf[SWZ(bo)];
                float2 a1 = buf[SWZ(bo + qq)];
                float2 a2 = buf[SWZ(bo + 2*qq)];
                float2 a3 = buf[SWZ(bo + 3*qq)];
                float2 t0 = cadd(a0, a2), t1 = csub(a0, a2);
                float2 t2 = cadd(a1, a3), t3 = csub(a1, a3);
                float2 y0 = cadd(t0, t2);
                float2 y1 = make_float2(t1.x + t3.y, t1.y - t3.x);  // t1 - i*t3
                float2 y2 = csub(t0, t2);
                float2 y3 = make_float2(t1.x - t3.y, t1.y + t3.x);  // t1 + i*t3
                float sn, cs; __sincosf(fac * (float)j, &sn, &cs);
                float2 w1 = make_float2(cs, sn);
                float2 w2 = cmul(w1, w1);
                float2 w3 = cmul(w2, w1);
                buf[SWZ(bo)]        = y0;
                buf[SWZ(bo + qq)]   = cmul(y1, w1);
                buf[SWZ(bo + 2*qq)] = cmul(y2, w2);
                buf[SWZ(bo + 3*qq)] = cmul(y3, w3);
            }
            __syncthreads();
        }
    };
    auto prod = [&]() {     // T += X * conj(Y), permuted order is fine
#pragma unroll
        for (int j = 0; j < 8; ++j) {
            const int f = tid + (j << 9);
            float2 x = bufs[0][SWZ(f)];
            float2 y = bufs[1][SWZ(f)];
            Tacc[j].x += x.x*y.x + x.y*y.y;
            Tacc[j].y += x.y*y.x - x.x*y.y;
        }
    };

    // pair 0: load low 16B of the block's 32B row-slice, stash pair 1
#pragma unroll
    for (int k2 = 0; k2 < 16; ++k2) {
        const int t = ttid + (k2 << 8);
        const float4 lo = *reinterpret_cast<const float4*>(base + (size_t)t * DDIM);
        buf[SWZ(t)] = make_float2(lo.x, lo.y);
        r1[k2] = make_float2(lo.z, lo.w);
    }
    __syncthreads();
    fftfwd(); prod();
    __syncthreads();

    // pair 1: store stash; issue high-16B loads (consumed after pair-1 FFT)
#pragma unroll
    for (int k2 = 0; k2 < 16; ++k2) {
        const int t = ttid + (k2 << 8);
        buf[SWZ(t)] = r1[k2];
        const float4 hi = *reinterpret_cast<const float4*>(base + (size_t)t * DDIM + 4);
        r2[k2] = make_float2(hi.x, hi.y);
        r3[k2] = make_float2(hi.z, hi.w);
    }
    __syncthreads();
    fftfwd(); prod();
    __syncthreads();

    // pair 2
#pragma unroll
    for (int k2 = 0; k2 < 16; ++k2) buf[SWZ(ttid + (k2 << 8))] = r2[k2];
    __syncthreads();
    fftfwd(); prod();
    __syncthreads();

    // pair 3
#pragma unroll
    for (int k2 = 0; k2 < 16; ++k2) buf[SWZ(ttid + (k2 << 8))] = r3[k2];
    __syncthreads();
    fftfwd(); prod();

    // accumulate into per-b spectrum (h-sum + split-sum fused)
    float2* To = Tb + (size_t)b * LSEQ;
#pragma unroll
    for (int j = 0; j < 8; ++j) {
        const int f = tid + (j << 9);
        atomicAdd(&To[f].x, Tacc[j].x);
        atomicAdd(&To[f].y, Tacc[j].y);
    }
}

// ---------------- Phase B: inverse FFT -> mean_value[b,tau] -------------------
// grid 8 (one per b), block 256
__global__ __launch_bounds__(256) void icorr_kernel(
    const float2* __restrict__ Tb, float* __restrict__ mv)
{
    __shared__ float2 z[LSEQ];   // 32KB
    const int b   = blockIdx.x;
    const int tid = threadIdx.x;

    for (int f = tid; f < LSEQ; f += 256) z[SWZ(f)] = Tb[(size_t)b * LSEQ + f];
    __syncthreads();

    // exact inverse of the DIF forward: conjugate twiddles on inputs, inverse butterfly
    for (int ls = 2; ls <= 12; ls += 2) {
        const int qq = 1 << (ls - 2);
        const float fac = 6.2831853071795864769f / (float)(1 << ls);
#pragma unroll
        for (int vv = 0; vv < 4; ++vv) {
            const int v  = tid + (vv << 8);
            const int bk = v >> (ls - 2);
            const int j  = v & (qq - 1);
            const int bo = (bk << ls) + j;
            float sn, cs; __sincosf(fac * (float)j, &sn, &cs);
            float2 w1 = make_float2(cs, sn);
            float2 w2 = cmul(w1, w1);
            float2 w3 = cmul(w2, w1);
            float2 u0 = z[SWZ(bo)];
            float2 u1 = cmul(z[SWZ(bo + qq)],   w1);
            float2 u2 = cmul(z[SWZ(bo + 2*qq)], w2);
            float2 u3 = cmul(z[SWZ(bo + 3*qq)], w3);
            float2 t0 = cadd(u0, u2), t1 = csub(u0, u2);
            float2 t2 = cadd(u1, u3), t3 = csub(u1, u3);
            z[SWZ(bo)]        = cadd(t0, t2);
            z[SWZ(bo + qq)]   = make_float2(t1.x - t3.y, t1.y + t3.x);  // t1 + i*t3
            z[SWZ(bo + 2*qq)] = csub(t0, t2);
            z[SWZ(bo + 3*qq)] = make_float2(t1.x + t3.y, t1.y - t3.x); // t1 - i*t3
        }
        __syncthreads();
    }

    const float scale = 1.0f / (4096.0f * 512.0f);  // 1/N (ifft) * 1/(H*D) (mean)
    for (int t = tid; t < LSEQ; t += 256) mv[(size_t)b * LSEQ + t] = z[SWZ(t)].x * scale;
}

// ---------------- Phase C: top-8 + softmax weights -----------------------------
__global__ __launch_bounds__(256) void topk_kernel(
    const float* __restrict__ mv, int* __restrict__ idx_out, float* __restrict__ w_out)
{
    __shared__ float gsm[LSEQ];
    __shared__ float rv[256];
    __shared__ int   ri[256];
    __shared__ int   topidx[TOPK];
    const int tid = threadIdx.x;

    for (int f = tid; f < LSEQ; f += 256) {
        float s = 0.f;
#pragma unroll
        for (int b = 0; b < NB; ++b) s += mv[b * LSEQ + f];
        gsm[f] = s;   // mean over b is monotone -> same argmax set
    }
    __syncthreads();

    for (int k = 0; k < TOPK; ++k) {
        float bv = -INFINITY; int bi = -1;
        for (int f = tid; f < LSEQ; f += 256) {
            float v = gsm[f];
            if (v > bv) { bv = v; bi = f; }
        }
        rv[tid] = bv; ri[tid] = bi;
        __syncthreads();
        for (int s2 = 128; s2 > 0; s2 >>= 1) {
            if (tid < s2) {
                if (rv[tid + s2] > rv[tid]) { rv[tid] = rv[tid + s2]; ri[tid] = ri[tid + s2]; }
            }
            __syncthreads();
        }
        if (tid == 0) { topidx[k] = ri[0]; gsm[ri[0]] = -INFINITY; }
        __syncthreads();
    }

    if (tid < NB) {
        const int b = tid;
        float wv[TOPK]; float mx = -INFINITY;
#pragma unroll
        for (int k = 0; k < TOPK; ++k) { wv[k] = mv[b * LSEQ + topidx[k]]; mx = fmaxf(mx, wv[k]); }
        float se = 0.f;
#pragma unroll
        for (int k = 0; k < TOPK; ++k) { wv[k] = expf(wv[k] - mx); se += wv[k]; }
#pragma unroll
        for (int k = 0; k < TOPK; ++k) w_out[b * TOPK + k] = wv[k] / se;
    }
    if (tid < TOPK) idx_out[tid] = topidx[tid];
}

// ---------------- Phase D: weighted circular-shift gather ----------------------
// grid B*H*(L/16) = 16384, block 256; thread -> (row, float4-slot)
__global__ __launch_bounds__(256) void gather_kernel(
    const float* __restrict__ V, const int* __restrict__ idxs,
    const float* __restrict__ w, float* __restrict__ out)
{
    const int blk = blockIdx.x;
    const int bh  = blk >> 8;
    const int l0  = (blk & 255) << 4;
    const int b   = bh >> 3;

    __shared__ int   sidx[TOPK];
    __shared__ float sw[TOPK];
    if (threadIdx.x < TOPK) {
        sidx[threadIdx.x] = idxs[threadIdx.x];
        sw[threadIdx.x]   = w[b * TOPK + threadIdx.x];
    }
    __syncthreads();

    const float4* Vb = reinterpret_cast<const float4*>(V + (size_t)bh * (LSEQ * DDIM));
    float4*       Ob = reinterpret_cast<float4*>(out + (size_t)bh * (LSEQ * DDIM));
    const int r  = threadIdx.x >> 4;
    const int qd = threadIdx.x & 15;
    const int l  = l0 + r;

    float4 acc = make_float4(0.f, 0.f, 0.f, 0.f);
#pragma unroll
    for (int k = 0; k < TOPK; ++k) {
        const int lv = (l + sidx[k]) & (LSEQ - 1);
        const float4 vv = Vb[(size_t)lv * 16 + qd];
        const float wk = sw[k];
        acc.x += wk * vv.x; acc.y += wk * vv.y;
        acc.z += wk * vv.z; acc.w += wk * vv.w;
    }
    Ob[(size_t)l * 16 + qd] = acc;
}

extern "C" void kernel_launch(void* const* d_in, const int* in_sizes, int n_in,
                              void* d_out, int out_size, void* d_ws, size_t ws_size,
                              hipStream_t stream)
{
    const float* Q = (const float*)d_in[0];
    const float* K = (const float*)d_in[1];
    const float* V = (const float*)d_in[2];
    float* out = (float*)d_out;

    char* ws = (char*)d_ws;
    float2* Tb  = (float2*)ws;                                        // 8*4096*8B = 256KB
    float*  mv  = (float*)(ws + (size_t)NB * LSEQ * sizeof(float2));  // 8*4096*4B = 128KB
    int*    idx = (int*)((char*)mv + (size_t)NB * LSEQ * sizeof(float));
    float*  w   = (float*)((char*)idx + 64);

    hipMemsetAsync(Tb, 0, (size_t)NB * LSEQ * sizeof(float2), stream);
    corr_fft_kernel<<<dim3(512), dim3(512), 0, stream>>>(Q, K, Tb);
    icorr_kernel  <<<dim3(NB),  dim3(256), 0, stream>>>(Tb, mv);
    topk_kernel   <<<dim3(1),   dim3(256), 0, stream>>>(mv, idx, w);
    gather_kernel <<<dim3(NB * NH * (LSEQ / 16)), dim3(256), 0, stream>>>(V, idx, w, out);
}

// Round 4
// 375.082 us; speedup vs baseline: 2.3226x; 1.1314x over previous
//
#include <hip/hip_runtime.h>
#include <math.h>

// AutoCorrelation (Autoformer) for B=8, H=8, L=4096, D=64, top_k=8.
// Phase A: cross-spectra summed over h and d: Tb[b,f] = sum_{h,d-pairs} FFT(Qpair)*conj(FFT(Kpair))
//          (512 blocks; 4 d-pairs per block; float atomicAdd reduction)
// Phase B: per-b inverse FFT -> mean_value[b,tau]
// Phase C: top-8 lags of batch-mean + per-b softmax weights
// Phase D: out[b,h,l,:] = sum_k w[b,k] * V[b,h,(l+idx_k)%L,:]

#define LSEQ 4096
#define DDIM 64
#define NB 8
#define NH 8
#define TOPK 8

// LDS bank swizzle for float2 elements: uniform 4-lane/slot (minimum for b64)
// across all radix-4 strides {1,4,16,64,256,1024} and linear access.
#define SWZ(i) ((i) ^ (((i) >> 4) & 15))

__device__ __forceinline__ float2 cadd(float2 a, float2 b){ return make_float2(a.x+b.x, a.y+b.y); }
__device__ __forceinline__ float2 csub(float2 a, float2 b){ return make_float2(a.x-b.x, a.y-b.y); }
__device__ __forceinline__ float2 cmul(float2 a, float2 b){ return make_float2(a.x*b.x - a.y*b.y, a.x*b.y + a.y*b.x); }

// ---------------- Phase A -----------------------------------------------------
// grid 512. XCD-swizzled decode: q8 = blk>>6, bh = blk&63, so the 8 split-blocks
// of one (b,h) all have blk%8 == bh%8 -> same XCD -> shared L2 for the 2MB
// row working set (each block reads a 32B slice of each 256B row).
// launch_bounds(512,2): LDS (64KB) caps at 2 blocks/CU anyway; allow ~256 VGPR
// so the r1/r2/r3 stashes (96 VGPRs) don't spill to scratch.
__global__ __launch_bounds__(512, 2) void corr_fft_kernel(
    const float* __restrict__ Q, const float* __restrict__ K,
    float2* __restrict__ Tb)
{
    __shared__ float2 bufs[2][LSEQ];   // 2 x 32KB = 64KB
    const int blk  = blockIdx.x;
    const int q8   = blk >> 6;         // 0..7  (d-pair group)
    const int bh   = blk & 63;         // 0..63 (b,h)
    const int b    = bh >> 3;
    const int tid  = threadIdx.x;
    const int team = tid >> 8;
    const int ttid = tid & 255;
    const float* src  = team ? K : Q;
    const float* base = src + (size_t)bh * (LSEQ * DDIM) + q8 * 8;
    float2* buf = bufs[team];

    float2 Tacc[8];
#pragma unroll
    for (int j = 0; j < 8; ++j) Tacc[j] = make_float2(0.f, 0.f);

    float2 r1[16], r2[16], r3[16];

    auto fftfwd = [&]() {   // radix-4 DIF, natural -> digit-reversed order
        for (int ls = 12; ls >= 2; ls -= 2) {
            const int qq = 1 << (ls - 2);
            const float fac = -6.2831853071795864769f / (float)(1 << ls);
#pragma unroll
            for (int vv = 0; vv < 4; ++vv) {
                const int v  = ttid + (vv << 8);
                const int bk = v >> (ls - 2);
                const int j  = v & (qq - 1);
                const int bo = (bk << ls) + j;
                float2 a0 = buf[SWZ(bo)];
                float2 a1 = buf[SWZ(bo + qq)];
                float2 a2 = buf[SWZ(bo + 2*qq)];
                float2 a3 = buf[SWZ(bo + 3*qq)];
                float2 t0 = cadd(a0, a2), t1 = csub(a0, a2);
                float2 t2 = cadd(a1, a3), t3 = csub(a1, a3);
                float2 y0 = cadd(t0, t2);
                float2 y1 = make_float2(t1.x + t3.y, t1.y - t3.x);  // t1 - i*t3
                float2 y2 = csub(t0, t2);
                float2 y3 = make_float2(t1.x - t3.y, t1.y + t3.x);  // t1 + i*t3
                float sn, cs; __sincosf(fac * (float)j, &sn, &cs);
                float2 w1 = make_float2(cs, sn);
                float2 w2 = cmul(w1, w1);
                float2 w3 = cmul(w2, w1);
                buf[SWZ(bo)]        = y0;
                buf[SWZ(bo + qq)]   = cmul(y1, w1);
                buf[SWZ(bo + 2*qq)] = cmul(y2, w2);
                buf[SWZ(bo + 3*qq)] = cmul(y3, w3);
            }
            __syncthreads();
        }
    };
    auto prod = [&]() {     // T += X * conj(Y), permuted order is fine
#pragma unroll
        for (int j = 0; j < 8; ++j) {
            const int f = tid + (j << 9);
            float2 x = bufs[0][SWZ(f)];
            float2 y = bufs[1][SWZ(f)];
            Tacc[j].x += x.x*y.x + x.y*y.y;
            Tacc[j].y += x.y*y.x - x.x*y.y;
        }
    };

    // pair 0: load low 16B of the block's 32B row-slice, stash pair 1
#pragma unroll
    for (int k2 = 0; k2 < 16; ++k2) {
        const int t = ttid + (k2 << 8);
        const float4 lo = *reinterpret_cast<const float4*>(base + (size_t)t * DDIM);
        buf[SWZ(t)] = make_float2(lo.x, lo.y);
        r1[k2] = make_float2(lo.z, lo.w);
    }
    __syncthreads();
    fftfwd(); prod();
    __syncthreads();

    // pair 1: store stash; issue high-16B loads (consumed after pair-1 FFT)
#pragma unroll
    for (int k2 = 0; k2 < 16; ++k2) {
        const int t = ttid + (k2 << 8);
        buf[SWZ(t)] = r1[k2];
        const float4 hi = *reinterpret_cast<const float4*>(base + (size_t)t * DDIM + 4);
        r2[k2] = make_float2(hi.x, hi.y);
        r3[k2] = make_float2(hi.z, hi.w);
    }
    __syncthreads();
    fftfwd(); prod();
    __syncthreads();

    // pair 2
#pragma unroll
    for (int k2 = 0; k2 < 16; ++k2) buf[SWZ(ttid + (k2 << 8))] = r2[k2];
    __syncthreads();
    fftfwd(); prod();
    __syncthreads();

    // pair 3
#pragma unroll
    for (int k2 = 0; k2 < 16; ++k2) buf[SWZ(ttid + (k2 << 8))] = r3[k2];
    __syncthreads();
    fftfwd(); prod();

    // accumulate into per-b spectrum (h-sum + split-sum fused)
    float2* To = Tb + (size_t)b * LSEQ;
#pragma unroll
    for (int j = 0; j < 8; ++j) {
        const int f = tid + (j << 9);
        atomicAdd(&To[f].x, Tacc[j].x);
        atomicAdd(&To[f].y, Tacc[j].y);
    }
}

// ---------------- Phase B: inverse FFT -> mean_value[b,tau] -------------------
// grid 8 (one per b), block 512 (2 butterflies/thread/stage)
__global__ __launch_bounds__(512) void icorr_kernel(
    const float2* __restrict__ Tb, float* __restrict__ mv)
{
    __shared__ float2 z[LSEQ];   // 32KB
    const int b   = blockIdx.x;
    const int tid = threadIdx.x;

    for (int f = tid; f < LSEQ; f += 512) z[SWZ(f)] = Tb[(size_t)b * LSEQ + f];
    __syncthreads();

    // exact inverse of the DIF forward: conjugate twiddles on inputs, inverse butterfly
    for (int ls = 2; ls <= 12; ls += 2) {
        const int qq = 1 << (ls - 2);
        const float fac = 6.2831853071795864769f / (float)(1 << ls);
#pragma unroll
        for (int vv = 0; vv < 2; ++vv) {
            const int v  = tid + (vv << 9);
            const int bk = v >> (ls - 2);
            const int j  = v & (qq - 1);
            const int bo = (bk << ls) + j;
            float sn, cs; __sincosf(fac * (float)j, &sn, &cs);
            float2 w1 = make_float2(cs, sn);
            float2 w2 = cmul(w1, w1);
            float2 w3 = cmul(w2, w1);
            float2 u0 = z[SWZ(bo)];
            float2 u1 = cmul(z[SWZ(bo + qq)],   w1);
            float2 u2 = cmul(z[SWZ(bo + 2*qq)], w2);
            float2 u3 = cmul(z[SWZ(bo + 3*qq)], w3);
            float2 t0 = cadd(u0, u2), t1 = csub(u0, u2);
            float2 t2 = cadd(u1, u3), t3 = csub(u1, u3);
            z[SWZ(bo)]        = cadd(t0, t2);
            z[SWZ(bo + qq)]   = make_float2(t1.x - t3.y, t1.y + t3.x);  // t1 + i*t3
            z[SWZ(bo + 2*qq)] = csub(t0, t2);
            z[SWZ(bo + 3*qq)] = make_float2(t1.x + t3.y, t1.y - t3.x); // t1 - i*t3
        }
        __syncthreads();
    }

    const float scale = 1.0f / (4096.0f * 512.0f);  // 1/N (ifft) * 1/(H*D) (mean)
    for (int t = tid; t < LSEQ; t += 512) mv[(size_t)b * LSEQ + t] = z[SWZ(t)].x * scale;
}

// ---------------- Phase C: top-8 + softmax weights -----------------------------
__global__ __launch_bounds__(256) void topk_kernel(
    const float* __restrict__ mv, int* __restrict__ idx_out, float* __restrict__ w_out)
{
    __shared__ float gsm[LSEQ];
    __shared__ float rv[256];
    __shared__ int   ri[256];
    __shared__ int   topidx[TOPK];
    const int tid = threadIdx.x;

    for (int f = tid; f < LSEQ; f += 256) {
        float s = 0.f;
#pragma unroll
        for (int b = 0; b < NB; ++b) s += mv[b * LSEQ + f];
        gsm[f] = s;   // mean over b is monotone -> same argmax set
    }
    __syncthreads();

    for (int k = 0; k < TOPK; ++k) {
        float bv = -INFINITY; int bi = -1;
        for (int f = tid; f < LSEQ; f += 256) {
            float v = gsm[f];
            if (v > bv) { bv = v; bi = f; }
        }
        rv[tid] = bv; ri[tid] = bi;
        __syncthreads();
        for (int s2 = 128; s2 > 0; s2 >>= 1) {
            if (tid < s2) {
                if (rv[tid + s2] > rv[tid]) { rv[tid] = rv[tid + s2]; ri[tid] = ri[tid + s2]; }
            }
            __syncthreads();
        }
        if (tid == 0) { topidx[k] = ri[0]; gsm[ri[0]] = -INFINITY; }
        __syncthreads();
    }

    if (tid < NB) {
        const int b = tid;
        float wv[TOPK]; float mx = -INFINITY;
#pragma unroll
        for (int k = 0; k < TOPK; ++k) { wv[k] = mv[b * LSEQ + topidx[k]]; mx = fmaxf(mx, wv[k]); }
        float se = 0.f;
#pragma unroll
        for (int k = 0; k < TOPK; ++k) { wv[k] = expf(wv[k] - mx); se += wv[k]; }
#pragma unroll
        for (int k = 0; k < TOPK; ++k) w_out[b * TOPK + k] = wv[k] / se;
    }
    if (tid < TOPK) idx_out[tid] = topidx[tid];
}

// ---------------- Phase D: weighted circular-shift gather ----------------------
// grid B*H*(L/16) = 16384, block 256; XCD-swizzled decode: bh = blk&63, so all
// 256 blocks of one (b,h) share an XCD -> its 1MB V-slice lives in that L2 and
// the 8 shifted re-reads are L2 hits.
__global__ __launch_bounds__(256) void gather_kernel(
    const float* __restrict__ V, const int* __restrict__ idxs,
    const float* __restrict__ w, float* __restrict__ out)
{
    const int blk = blockIdx.x;
    const int bh  = blk & 63;
    const int l0  = (blk >> 6) << 4;
    const int b   = bh >> 3;

    __shared__ int   sidx[TOPK];
    __shared__ float sw[TOPK];
    if (threadIdx.x < TOPK) {
        sidx[threadIdx.x] = idxs[threadIdx.x];
        sw[threadIdx.x]   = w[b * TOPK + threadIdx.x];
    }
    __syncthreads();

    const float4* Vb = reinterpret_cast<const float4*>(V + (size_t)bh * (LSEQ * DDIM));
    float4*       Ob = reinterpret_cast<float4*>(out + (size_t)bh * (LSEQ * DDIM));
    const int r  = threadIdx.x >> 4;
    const int qd = threadIdx.x & 15;
    const int l  = l0 + r;

    float4 acc = make_float4(0.f, 0.f, 0.f, 0.f);
#pragma unroll
    for (int k = 0; k < TOPK; ++k) {
        const int lv = (l + sidx[k]) & (LSEQ - 1);
        const float4 vv = Vb[(size_t)lv * 16 + qd];
        const float wk = sw[k];
        acc.x += wk * vv.x; acc.y += wk * vv.y;
        acc.z += wk * vv.z; acc.w += wk * vv.w;
    }
    Ob[(size_t)l * 16 + qd] = acc;
}

extern "C" void kernel_launch(void* const* d_in, const int* in_sizes, int n_in,
                              void* d_out, int out_size, void* d_ws, size_t ws_size,
                              hipStream_t stream)
{
    const float* Q = (const float*)d_in[0];
    const float* K = (const float*)d_in[1];
    const float* V = (const float*)d_in[2];
    float* out = (float*)d_out;

    char* ws = (char*)d_ws;
    float2* Tb  = (float2*)ws;                                        // 8*4096*8B = 256KB
    float*  mv  = (float*)(ws + (size_t)NB * LSEQ * sizeof(float2));  // 8*4096*4B = 128KB
    int*    idx = (int*)((char*)mv + (size_t)NB * LSEQ * sizeof(float));
    float*  w   = (float*)((char*)idx + 64);

    hipMemsetAsync(Tb, 0, (size_t)NB * LSEQ * sizeof(float2), stream);
    corr_fft_kernel<<<dim3(512), dim3(512), 0, stream>>>(Q, K, Tb);
    icorr_kernel  <<<dim3(NB),  dim3(512), 0, stream>>>(Tb, mv);
    topk_kernel   <<<dim3(1),   dim3(256), 0, stream>>>(mv, idx, w);
    gather_kernel <<<dim3(NB * NH * (LSEQ / 16)), dim3(256), 0, stream>>>(V, idx, w, out);
}